// Round 1
// baseline (979.696 us; speedup 1.0000x reference)
//
#include <hip/hip_runtime.h>
#include <stdint.h>
#include <math.h>

#define NPTS 2048
#define BSZ 8
#define KNN 16
#define MROWS (BSZ * NPTS)   // 16384

// ---------- helpers ----------
__device__ __forceinline__ unsigned sortable32(float f) {
    unsigned u = __float_as_uint(f);
    return u ^ ((unsigned)((int)u >> 31) | 0x80000000u);
}

__device__ __forceinline__ void cas_asc(unsigned long long &a, unsigned long long &b) {
    unsigned long long lo = a < b ? a : b;
    unsigned long long hi = a < b ? b : a;
    a = lo; b = hi;
}

// ---------- KNN + covariance features ----------
// grid: B * N/4 = 4096 blocks, 256 threads (4 waves), one query per wave.
__global__ __launch_bounds__(256)
void knn_cov_kernel(const float* __restrict__ x,     // (B,3,N)
                    const int*   __restrict__ mask,  // (B,N)
                    int*   __restrict__ idx_out,     // (B*N,16)  global row ids
                    float* __restrict__ h0)          // (B*N,12)
{
    __shared__ float4 cand[NPTS];   // x,y,z, sq (or +inf if masked)
    const int tid  = threadIdx.x;
    const int wave = tid >> 6;
    const int lane = tid & 63;
    const int b = blockIdx.x >> 9;                 // 512 blocks per batch
    const int q = ((blockIdx.x & 511) << 2) + wave;
    const float* xb = x + (size_t)b * 3 * NPTS;
    const int*   mb = mask + b * NPTS;

    for (int m = tid; m < NPTS; m += 256) {
        float px = xb[m], py = xb[NPTS + m], pz = xb[2 * NPTS + m];
        float sq = px * px + py * py + pz * pz;
        if (mb[m] != 1) sq = INFINITY;
        cand[m] = make_float4(px, py, pz, sq);
    }
    __syncthreads();

    const float4 qc = cand[q];
    const float qx = qc.x, qy = qc.y, qz = qc.z;
    const float sqn = qx * qx + qy * qy + qz * qz;

    // phase 1: 32 candidates per lane, packed keys
    unsigned long long key[32];
    #pragma unroll
    for (int t = 0; t < 32; ++t) {
        const int m = t * 64 + lane;
        const float4 c = cand[m];
        const float dot = qx * c.x + qy * c.y + qz * c.z;
        const float d = fmaf(-2.f, dot, sqn + c.w);
        key[t] = ((unsigned long long)sortable32(d) << 32) | (unsigned)m;
    }
    // branchless bitonic sort of 32 keys (ascending)
    #pragma unroll
    for (int k = 2; k <= 32; k <<= 1) {
        #pragma unroll
        for (int j = k >> 1; j > 0; j >>= 1) {
            #pragma unroll
            for (int i = 0; i < 32; ++i) {
                const int l = i ^ j;
                if (l > i) {
                    if ((i & k) == 0) cas_asc(key[i], key[l]);
                    else              cas_asc(key[l], key[i]);
                }
            }
        }
    }
    // 6 cross-lane bitonic merge rounds: keep lowest 16 of (mine, partner)
    #pragma unroll
    for (int p = 1; p <= 32; p <<= 1) {
        unsigned long long c[16];
        #pragma unroll
        for (int i = 0; i < 16; ++i) {
            unsigned long long pr = __shfl_xor(key[15 - i], p, 64);
            c[i] = key[i] < pr ? key[i] : pr;
        }
        #pragma unroll
        for (int j = 8; j > 0; j >>= 1) {
            #pragma unroll
            for (int i = 0; i < 16; ++i) {
                const int l = i ^ j;
                if (l > i) cas_asc(c[i], c[l]);
            }
        }
        #pragma unroll
        for (int i = 0; i < 16; ++i) key[i] = c[i];
    }

    const int gq = b * NPTS + q;
    if (lane < KNN)
        idx_out[gq * KNN + lane] = b * NPTS + (int)(unsigned)key[lane];

    // covariance: lanes 0..15 each hold one neighbor
    const int ml = (int)(unsigned)key[lane & 15];
    const float4 nb = cand[ml];
    float sx = nb.x, sy = nb.y, sz = nb.z;
    #pragma unroll
    for (int m = 1; m < 16; m <<= 1) {
        sx += __shfl_xor(sx, m, 64);
        sy += __shfl_xor(sy, m, 64);
        sz += __shfl_xor(sz, m, 64);
    }
    const float mx = sx * 0.0625f, my = sy * 0.0625f, mz = sz * 0.0625f;
    const float cx = nb.x - mx, cy = nb.y - my, cz = nb.z - mz;
    float xx = cx * cx, xy = cx * cy, xz = cx * cz;
    float yy = cy * cy, yz = cy * cz, zz = cz * cz;
    #pragma unroll
    for (int m = 1; m < 16; m <<= 1) {
        xx += __shfl_xor(xx, m, 64);
        xy += __shfl_xor(xy, m, 64);
        xz += __shfl_xor(xz, m, 64);
        yy += __shfl_xor(yy, m, 64);
        yz += __shfl_xor(yz, m, 64);
        zz += __shfl_xor(zz, m, 64);
    }
    if (lane == 0) {
        float* o = h0 + (size_t)gq * 12;
        o[0] = qx; o[1] = qy; o[2] = qz;
        o[3] = xx; o[4] = xy; o[5] = xz;
        o[6] = xy; o[7] = yy; o[8] = yz;
        o[9] = xz; o[10] = yz; o[11] = zz;
    }
}

// ---------- generic fp32 GEMM: Y(M x C) = X(M x K) @ W(K x C) + bias ----------
// grid: (M/64, C/64), 256 threads, 4x4 micro-tile
__global__ __launch_bounds__(256)
void gemm_bias_kernel(const float* __restrict__ X, const float* __restrict__ W,
                      const float* __restrict__ bias, float* __restrict__ Y,
                      int K, int C)
{
    __shared__ float Xs[16][65];
    __shared__ float Ws[16][65];
    const int tid = threadIdx.x;
    const int bm = blockIdx.x << 6;
    const int bn = blockIdx.y << 6;
    const int ty = tid >> 4, tx = tid & 15;
    float acc[4][4] = {};
    for (int k0 = 0; k0 < K; k0 += 16) {
        #pragma unroll
        for (int e = tid; e < 1024; e += 256) {
            const int m = e >> 4, k = e & 15;
            Xs[k][m] = (k0 + k < K) ? X[(size_t)(bm + m) * K + k0 + k] : 0.f;
        }
        #pragma unroll
        for (int e = tid; e < 1024; e += 256) {
            const int k = e >> 6, n = e & 63;
            Ws[k][n] = (k0 + k < K) ? W[(size_t)(k0 + k) * C + bn + n] : 0.f;
        }
        __syncthreads();
        #pragma unroll
        for (int k = 0; k < 16; ++k) {
            float a[4], bb[4];
            #pragma unroll
            for (int i = 0; i < 4; ++i) a[i] = Xs[k][ty * 4 + i];
            #pragma unroll
            for (int j = 0; j < 4; ++j) bb[j] = Ws[k][tx * 4 + j];
            #pragma unroll
            for (int i = 0; i < 4; ++i)
                #pragma unroll
                for (int j = 0; j < 4; ++j)
                    acc[i][j] = fmaf(a[i], bb[j], acc[i][j]);
        }
        __syncthreads();
    }
    #pragma unroll
    for (int i = 0; i < 4; ++i) {
        const int r = bm + ty * 4 + i;
        #pragma unroll
        for (int j = 0; j < 4; ++j) {
            const int cc = bn + tx * 4 + j;
            Y[(size_t)r * C + cc] = acc[i][j] + bias[cc];
        }
    }
}

// ---------- BN statistics: deterministic two-stage ----------
// grid: (C/64, 32) — each block: 512 rows x 64 channels partial sum/sumsq
__global__ __launch_bounds__(256)
void stats_partial_kernel(const float* __restrict__ Y, float* __restrict__ psum,
                          float* __restrict__ psumsq, int C)
{
    const int c = (blockIdx.x << 6) + (threadIdx.x & 63);
    const int rg = threadIdx.x >> 6;
    const int r0 = blockIdx.y * 512;
    float s = 0.f, ss = 0.f;
    for (int r = r0 + rg; r < r0 + 512; r += 4) {
        const float v = Y[(size_t)r * C + c];
        s += v; ss = fmaf(v, v, ss);
    }
    __shared__ float ls[256], lss[256];
    ls[threadIdx.x] = s; lss[threadIdx.x] = ss;
    __syncthreads();
    if (threadIdx.x < 64) {
        s  = ls[threadIdx.x]  + ls[threadIdx.x + 64]  + ls[threadIdx.x + 128]  + ls[threadIdx.x + 192];
        ss = lss[threadIdx.x] + lss[threadIdx.x + 64] + lss[threadIdx.x + 128] + lss[threadIdx.x + 192];
        psum[blockIdx.y * C + c] = s;
        psumsq[blockIdx.y * C + c] = ss;
    }
}

__global__ void stats_final_kernel(const float* __restrict__ psum, const float* __restrict__ psumsq,
                                   const float* __restrict__ g, const float* __restrict__ be,
                                   float* __restrict__ scale, float* __restrict__ shift, int C)
{
    const int c = blockIdx.x * 256 + threadIdx.x;
    if (c >= C) return;
    float s = 0.f, ss = 0.f;
    for (int i = 0; i < 32; ++i) { s += psum[i * C + c]; ss += psumsq[i * C + c]; }
    const float invM = 1.f / (float)MROWS;
    const float mean = s * invM;
    const float var = fmaxf(ss * invM - mean * mean, 0.f);
    const float sc = g[c] * rsqrtf(var + 1e-5f);
    scale[c] = sc;
    shift[c] = be[c] - mean * sc;
}

__global__ void bnrelu_kernel(float* __restrict__ Y, const float* __restrict__ scale,
                              const float* __restrict__ shift, int total4, int C)
{
    for (int i = blockIdx.x * blockDim.x + threadIdx.x; i < total4; i += gridDim.x * blockDim.x) {
        float4 v = ((float4*)Y)[i];
        const int c = (i * 4) % C;
        v.x = fmaxf(0.f, fmaf(v.x, scale[c],     shift[c]));
        v.y = fmaxf(0.f, fmaf(v.y, scale[c + 1], shift[c + 1]));
        v.z = fmaxf(0.f, fmaf(v.z, scale[c + 2], shift[c + 2]));
        v.w = fmaxf(0.f, fmaf(v.w, scale[c + 3], shift[c + 3]));
        ((float4*)Y)[i] = v;
    }
}

// ---------- gather-max over KNN graph ----------
template<int CH>
__global__ __launch_bounds__(256)
void gathermax_kernel(const float* __restrict__ Hin, const int* __restrict__ idx,
                      float* __restrict__ Z)
{
    constexpr int RPB = 256 / CH;
    const int rr = threadIdx.x / CH;
    const int c = threadIdx.x % CH;
    const int row = blockIdx.x * RPB + rr;
    const int* ip = idx + (size_t)row * KNN;
    float m = -INFINITY;
    #pragma unroll
    for (int k = 0; k < KNN; ++k) {
        const int j = ip[k];
        m = fmaxf(m, Hin[(size_t)j * CH + c]);
    }
    Z[(size_t)row * CH + c] = m;
}

// ---------- fused bnrelu + masked segment max (1024 ch) ----------
// grid: (8, 8, 4), 256 threads
__global__ __launch_bounds__(256)
void segmax_bnrelu_kernel(const float* __restrict__ H, const float* __restrict__ scale,
                          const float* __restrict__ shift, const int* __restrict__ mask,
                          unsigned* __restrict__ pooled)
{
    const int b = blockIdx.x, nc = blockIdx.y, cg = blockIdx.z;
    const int c = (cg << 8) + threadIdx.x;
    const float sc = scale[c], sh = shift[c];
    float m = 0.f;                       // identity: post-relu values >= 0
    const int n0 = nc << 8;
    for (int n = n0; n < n0 + 256; ++n) {
        if (mask[b * NPTS + n] == 1) {
            const float v = H[((size_t)b * NPTS + n) * 1024 + c];
            m = fmaxf(m, fmaxf(0.f, fmaf(v, sc, sh)));
        }
    }
    atomicMax(&pooled[(b << 10) + c], __float_as_uint(m));
}

// ---------- head: 8-row GEMM + BN(over 8) + ReLU, fused ----------
// grid: 8 blocks (64 cols each), 256 threads
template<int KDIM>
__global__ __launch_bounds__(256)
void mlp8_kernel(const float* __restrict__ In, const float* __restrict__ W,
                 const float* __restrict__ bias, const float* __restrict__ g,
                 const float* __restrict__ be, float* __restrict__ Out)
{
    __shared__ float Ins[8 * KDIM];
    __shared__ float Ys[8][64];
    const int tid = threadIdx.x;
    for (int e = tid; e < 8 * KDIM; e += 256) Ins[e] = In[e];
    __syncthreads();
    const int cl = tid & 63;
    const int col = (blockIdx.x << 6) + cl;
    const int r0 = tid >> 6;
    float a0 = 0.f, a1 = 0.f;
    for (int k = 0; k < KDIM; ++k) {
        const float w = W[(size_t)k * 512 + col];
        a0 = fmaf(Ins[r0 * KDIM + k], w, a0);
        a1 = fmaf(Ins[(r0 + 4) * KDIM + k], w, a1);
    }
    const float bi = bias[col];
    Ys[r0][cl] = a0 + bi;
    Ys[r0 + 4][cl] = a1 + bi;
    __syncthreads();
    if (tid < 64) {
        float s = 0.f, ss = 0.f;
        #pragma unroll
        for (int r = 0; r < 8; ++r) { const float v = Ys[r][tid]; s += v; ss = fmaf(v, v, ss); }
        const float mean = s * 0.125f;
        const float var = fmaxf(ss * 0.125f - mean * mean, 0.f);
        const float sc = g[col] * rsqrtf(var + 1e-5f);
        const float sh = be[col] - mean * sc;
        #pragma unroll
        for (int r = 0; r < 8; ++r)
            Out[r * 512 + col] = fmaxf(0.f, fmaf(Ys[r][tid], sc, sh));
    }
}

// ---------- launcher ----------
extern "C" void kernel_launch(void* const* d_in, const int* in_sizes, int n_in,
                              void* d_out, int out_size, void* d_ws, size_t ws_size,
                              hipStream_t stream)
{
    const float* x    = (const float*)d_in[0];
    const int*   mask = (const int*)d_in[1];
    const float* w_m1a = (const float*)d_in[2];
    const float* b_m1a = (const float*)d_in[3];
    const float* g_m1a = (const float*)d_in[4];
    const float* be_m1a = (const float*)d_in[5];
    const float* w_m1b = (const float*)d_in[6];
    const float* b_m1b = (const float*)d_in[7];
    const float* g_m1b = (const float*)d_in[8];
    const float* be_m1b = (const float*)d_in[9];
    const float* w_m1c = (const float*)d_in[10];
    const float* b_m1c = (const float*)d_in[11];
    const float* g_m1c = (const float*)d_in[12];
    const float* be_m1c = (const float*)d_in[13];
    const float* w_gl1 = (const float*)d_in[14];
    const float* b_gl1 = (const float*)d_in[15];
    const float* g_gl1 = (const float*)d_in[16];
    const float* be_gl1 = (const float*)d_in[17];
    const float* w_gl2 = (const float*)d_in[18];
    const float* b_gl2 = (const float*)d_in[19];
    const float* g_gl2 = (const float*)d_in[20];
    const float* be_gl2 = (const float*)d_in[21];
    const float* w_m2a = (const float*)d_in[22];
    const float* b_m2a = (const float*)d_in[23];
    const float* g_m2a = (const float*)d_in[24];
    const float* be_m2a = (const float*)d_in[25];
    const float* w_m2b = (const float*)d_in[26];
    const float* b_m2b = (const float*)d_in[27];
    const float* g_m2b = (const float*)d_in[28];
    const float* be_m2b = (const float*)d_in[29];

    float* ws = (float*)d_ws;
    int*   idx  = (int*)ws;                 // 262144 ints (1 MB)
    float* h0   = ws + 262144;              // 16384*12
    float* bufA = h0 + 196608;              // 16384*64
    float* bufB = bufA + 1048576;           // 16384*64
    float* bufC = bufB + 1048576;           // 16384*128
    float* bufD = bufC + 2097152;           // 16384*128
    float* bufE = bufD + 2097152;           // 16384*1024
    float* pooled = bufE + 16777216;        // 8*1024
    float* y1     = pooled + 8192;          // 8*512
    float* psum   = y1 + 4096;              // 32*1024
    float* psumsq = psum + 32768;           // 32*1024
    float* scale  = psumsq + 32768;         // 1024
    float* shift  = scale + 1024;           // 1024

    hipMemsetAsync(pooled, 0, 8 * 1024 * sizeof(float), stream);

    knn_cov_kernel<<<4096, 256, 0, stream>>>(x, mask, idx, h0);

    // m1a: 12 -> 64
    gemm_bias_kernel<<<dim3(256, 1), 256, 0, stream>>>(h0, w_m1a, b_m1a, bufA, 12, 64);
    stats_partial_kernel<<<dim3(1, 32), 256, 0, stream>>>(bufA, psum, psumsq, 64);
    stats_final_kernel<<<1, 256, 0, stream>>>(psum, psumsq, g_m1a, be_m1a, scale, shift, 64);
    bnrelu_kernel<<<1024, 256, 0, stream>>>(bufA, scale, shift, MROWS * 64 / 4, 64);

    // m1b: 64 -> 64
    gemm_bias_kernel<<<dim3(256, 1), 256, 0, stream>>>(bufA, w_m1b, b_m1b, bufB, 64, 64);
    stats_partial_kernel<<<dim3(1, 32), 256, 0, stream>>>(bufB, psum, psumsq, 64);
    stats_final_kernel<<<1, 256, 0, stream>>>(psum, psumsq, g_m1b, be_m1b, scale, shift, 64);
    bnrelu_kernel<<<1024, 256, 0, stream>>>(bufB, scale, shift, MROWS * 64 / 4, 64);

    // m1c: 64 -> 64
    gemm_bias_kernel<<<dim3(256, 1), 256, 0, stream>>>(bufB, w_m1c, b_m1c, bufA, 64, 64);
    stats_partial_kernel<<<dim3(1, 32), 256, 0, stream>>>(bufA, psum, psumsq, 64);
    stats_final_kernel<<<1, 256, 0, stream>>>(psum, psumsq, g_m1c, be_m1c, scale, shift, 64);
    bnrelu_kernel<<<1024, 256, 0, stream>>>(bufA, scale, shift, MROWS * 64 / 4, 64);

    // gather-max (64 ch)
    gathermax_kernel<64><<<4096, 256, 0, stream>>>(bufA, idx, bufB);

    // gl1: 64 -> 128
    gemm_bias_kernel<<<dim3(256, 2), 256, 0, stream>>>(bufB, w_gl1, b_gl1, bufC, 64, 128);
    stats_partial_kernel<<<dim3(2, 32), 256, 0, stream>>>(bufC, psum, psumsq, 128);
    stats_final_kernel<<<1, 256, 0, stream>>>(psum, psumsq, g_gl1, be_gl1, scale, shift, 128);
    bnrelu_kernel<<<2048, 256, 0, stream>>>(bufC, scale, shift, MROWS * 128 / 4, 128);

    // gather-max (128 ch)
    gathermax_kernel<128><<<8192, 256, 0, stream>>>(bufC, idx, bufD);

    // gl2: 128 -> 1024
    gemm_bias_kernel<<<dim3(256, 16), 256, 0, stream>>>(bufD, w_gl2, b_gl2, bufE, 128, 1024);
    stats_partial_kernel<<<dim3(16, 32), 256, 0, stream>>>(bufE, psum, psumsq, 1024);
    stats_final_kernel<<<4, 256, 0, stream>>>(psum, psumsq, g_gl2, be_gl2, scale, shift, 1024);

    // fused bnrelu + masked segment-max pool
    segmax_bnrelu_kernel<<<dim3(8, 8, 4), 256, 0, stream>>>(bufE, scale, shift, mask, (unsigned*)pooled);

    // head
    mlp8_kernel<1024><<<8, 256, 0, stream>>>(pooled, w_m2a, b_m2a, g_m2a, be_m2a, y1);
    mlp8_kernel<512><<<8, 256, 0, stream>>>(y1, w_m2b, b_m2b, g_m2b, be_m2b, (float*)d_out);
}

// Round 2
// 589.635 us; speedup vs baseline: 1.6615x; 1.6615x over previous
//
#include <hip/hip_runtime.h>
#include <stdint.h>
#include <math.h>

#define NPTS 2048
#define BSZ 8
#define KNN 16
#define MROWS (BSZ * NPTS)   // 16384

// ---------- helpers ----------
__device__ __forceinline__ unsigned sortable32(float f) {
    unsigned u = __float_as_uint(f);
    return u ^ ((unsigned)((int)u >> 31) | 0x80000000u);
}

__device__ __forceinline__ void cas_asc(unsigned long long &a, unsigned long long &b) {
    unsigned long long lo = a < b ? a : b;
    unsigned long long hi = a < b ? b : a;
    a = lo; b = hi;
}

// ---------- KNN + covariance features ----------
// grid: B * N/4 = 4096 blocks, 256 threads (4 waves), one query per wave.
// Per lane: branchless insertion top-16 of its 32 candidates (32 VGPRs of
// sorted state, no spill), then 6 cross-lane bitonic merge rounds.
__global__ __launch_bounds__(256)
void knn_cov_kernel(const float* __restrict__ x,     // (B,3,N)
                    const int*   __restrict__ mask,  // (B,N)
                    int*   __restrict__ idx_out,     // (B*N,16)  global row ids
                    float* __restrict__ h0)          // (B*N,12)
{
    __shared__ float4 cand[NPTS];   // x,y,z, sq (or +inf if masked)
    const int tid  = threadIdx.x;
    const int wave = tid >> 6;
    const int lane = tid & 63;
    const int b = blockIdx.x >> 9;                 // 512 blocks per batch
    const int q = ((blockIdx.x & 511) << 2) + wave;
    const float* xb = x + (size_t)b * 3 * NPTS;
    const int*   mb = mask + b * NPTS;

    for (int m = tid; m < NPTS; m += 256) {
        float px = xb[m], py = xb[NPTS + m], pz = xb[2 * NPTS + m];
        float sq = px * px + py * py + pz * pz;
        if (mb[m] != 1) sq = INFINITY;
        cand[m] = make_float4(px, py, pz, sq);
    }
    __syncthreads();

    const float4 qc = cand[q];
    const float qx = qc.x, qy = qc.y, qz = qc.z;
    const float sqn = qx * qx + qy * qy + qz * qz;

    // per-lane top-16 via branchless bubble insertion (ascending)
    unsigned long long list[16];
    #pragma unroll
    for (int i = 0; i < 16; ++i) list[i] = ~0ull;
    #pragma unroll
    for (int t = 0; t < 32; ++t) {
        const int m = t * 64 + lane;
        const float4 c = cand[m];
        const float dot = qx * c.x + qy * c.y + qz * c.z;
        const float d = fmaf(-2.f, dot, sqn + c.w);
        unsigned long long cur = ((unsigned long long)sortable32(d) << 32) | (unsigned)m;
        #pragma unroll
        for (int i = 0; i < 16; ++i) {
            const bool lt = cur < list[i];
            const unsigned long long lo = lt ? cur : list[i];
            const unsigned long long hi = lt ? list[i] : cur;
            list[i] = lo; cur = hi;
        }
    }

    // 6 cross-lane bitonic merge rounds: keep lowest 16 of (mine, partner)
    #pragma unroll
    for (int p = 1; p <= 32; p <<= 1) {
        unsigned long long c2[16];
        #pragma unroll
        for (int i = 0; i < 16; ++i) {
            const unsigned long long pr = __shfl_xor(list[15 - i], p, 64);
            c2[i] = list[i] < pr ? list[i] : pr;
        }
        #pragma unroll
        for (int j = 8; j > 0; j >>= 1) {
            #pragma unroll
            for (int i = 0; i < 16; ++i) {
                const int l = i ^ j;
                if (l > i) cas_asc(c2[i], c2[l]);
            }
        }
        #pragma unroll
        for (int i = 0; i < 16; ++i) list[i] = c2[i];
    }

    const int gq = b * NPTS + q;
    if (lane < KNN)
        idx_out[gq * KNN + lane] = b * NPTS + (int)(unsigned)list[lane];

    // covariance: lanes 0..15 each hold one neighbor (replicated x4)
    const int ml = (int)(unsigned)list[lane & 15];
    const float4 nb = cand[ml];
    float sx = nb.x, sy = nb.y, sz = nb.z;
    #pragma unroll
    for (int m = 1; m < 16; m <<= 1) {
        sx += __shfl_xor(sx, m, 64);
        sy += __shfl_xor(sy, m, 64);
        sz += __shfl_xor(sz, m, 64);
    }
    const float mx = sx * 0.0625f, my = sy * 0.0625f, mz = sz * 0.0625f;
    const float cx = nb.x - mx, cy = nb.y - my, cz = nb.z - mz;
    float xx = cx * cx, xy = cx * cy, xz = cx * cz;
    float yy = cy * cy, yz = cy * cz, zz = cz * cz;
    #pragma unroll
    for (int m = 1; m < 16; m <<= 1) {
        xx += __shfl_xor(xx, m, 64);
        xy += __shfl_xor(xy, m, 64);
        xz += __shfl_xor(xz, m, 64);
        yy += __shfl_xor(yy, m, 64);
        yz += __shfl_xor(yz, m, 64);
        zz += __shfl_xor(zz, m, 64);
    }
    if (lane == 0) {
        float* o = h0 + (size_t)gq * 12;
        o[0] = qx; o[1] = qy; o[2] = qz;
        o[3] = xx; o[4] = xy; o[5] = xz;
        o[6] = xy; o[7] = yy; o[8] = yz;
        o[9] = xz; o[10] = yz; o[11] = zz;
    }
}

// ---------- fp32 GEMM: Y(M x C) = bnx(X)(M x K) @ W(K x C) + bias ----------
// BNX: apply y=relu(x*scale+shift) to X elements while staging into LDS.
template<bool BNX>
__global__ __launch_bounds__(256)
void gemm_bias_kernel(const float* __restrict__ X, const float* __restrict__ W,
                      const float* __restrict__ bias,
                      const float* __restrict__ xscale, const float* __restrict__ xshift,
                      float* __restrict__ Y, int K, int C)
{
    __shared__ float Xs[16][65];
    __shared__ float Ws[16][65];
    const int tid = threadIdx.x;
    const int bm = blockIdx.x << 6;
    const int bn = blockIdx.y << 6;
    const int ty = tid >> 4, tx = tid & 15;
    float acc[4][4] = {};
    for (int k0 = 0; k0 < K; k0 += 16) {
        #pragma unroll
        for (int e = tid; e < 1024; e += 256) {
            const int m = e >> 4, k = e & 15;
            float v = 0.f;
            if (k0 + k < K) {
                v = X[(size_t)(bm + m) * K + k0 + k];
                if (BNX) v = fmaxf(0.f, fmaf(v, xscale[k0 + k], xshift[k0 + k]));
            }
            Xs[k][m] = v;
        }
        #pragma unroll
        for (int e = tid; e < 1024; e += 256) {
            const int k = e >> 6, n = e & 63;
            Ws[k][n] = (k0 + k < K) ? W[(size_t)(k0 + k) * C + bn + n] : 0.f;
        }
        __syncthreads();
        #pragma unroll
        for (int k = 0; k < 16; ++k) {
            float a[4], bb[4];
            #pragma unroll
            for (int i = 0; i < 4; ++i) a[i] = Xs[k][ty * 4 + i];
            #pragma unroll
            for (int j = 0; j < 4; ++j) bb[j] = Ws[k][tx * 4 + j];
            #pragma unroll
            for (int i = 0; i < 4; ++i)
                #pragma unroll
                for (int j = 0; j < 4; ++j)
                    acc[i][j] = fmaf(a[i], bb[j], acc[i][j]);
        }
        __syncthreads();
    }
    #pragma unroll
    for (int i = 0; i < 4; ++i) {
        const int r = bm + ty * 4 + i;
        #pragma unroll
        for (int j = 0; j < 4; ++j) {
            const int cc = bn + tx * 4 + j;
            Y[(size_t)r * C + cc] = acc[i][j] + bias[cc];
        }
    }
}

// ---------- BN statistics: deterministic two-stage ----------
__global__ __launch_bounds__(256)
void stats_partial_kernel(const float* __restrict__ Y, float* __restrict__ psum,
                          float* __restrict__ psumsq, int C)
{
    const int c = (blockIdx.x << 6) + (threadIdx.x & 63);
    const int rg = threadIdx.x >> 6;
    const int r0 = blockIdx.y * 512;
    float s = 0.f, ss = 0.f;
    for (int r = r0 + rg; r < r0 + 512; r += 4) {
        const float v = Y[(size_t)r * C + c];
        s += v; ss = fmaf(v, v, ss);
    }
    __shared__ float ls[256], lss[256];
    ls[threadIdx.x] = s; lss[threadIdx.x] = ss;
    __syncthreads();
    if (threadIdx.x < 64) {
        s  = ls[threadIdx.x]  + ls[threadIdx.x + 64]  + ls[threadIdx.x + 128]  + ls[threadIdx.x + 192];
        ss = lss[threadIdx.x] + lss[threadIdx.x + 64] + lss[threadIdx.x + 128] + lss[threadIdx.x + 192];
        psum[blockIdx.y * C + c] = s;
        psumsq[blockIdx.y * C + c] = ss;
    }
}

__global__ void stats_final_kernel(const float* __restrict__ psum, const float* __restrict__ psumsq,
                                   const float* __restrict__ g, const float* __restrict__ be,
                                   float* __restrict__ scale, float* __restrict__ shift, int C)
{
    const int c = blockIdx.x * 256 + threadIdx.x;
    if (c >= C) return;
    float s = 0.f, ss = 0.f;
    for (int i = 0; i < 32; ++i) { s += psum[i * C + c]; ss += psumsq[i * C + c]; }
    const float invM = 1.f / (float)MROWS;
    const float mean = s * invM;
    const float var = fmaxf(ss * invM - mean * mean, 0.f);
    const float sc = g[c] * rsqrtf(var + 1e-5f);
    scale[c] = sc;
    shift[c] = be[c] - mean * sc;
}

// ---------- gather-max over KNN graph, fused BN+ReLU on gathered elements ----------
template<int CH>
__global__ __launch_bounds__(256)
void gathermax_bn_kernel(const float* __restrict__ Hin, const int* __restrict__ idx,
                         const float* __restrict__ scale, const float* __restrict__ shift,
                         float* __restrict__ Z)
{
    constexpr int RPB = 256 / CH;
    const int rr = threadIdx.x / CH;
    const int c = threadIdx.x % CH;
    const int row = blockIdx.x * RPB + rr;
    const int* ip = idx + (size_t)row * KNN;
    const float sc = scale[c], sh = shift[c];
    float m = 0.f;   // post-ReLU values are >= 0
    #pragma unroll
    for (int k = 0; k < KNN; ++k) {
        const int j = ip[k];
        m = fmaxf(m, fmaf(Hin[(size_t)j * CH + c], sc, sh));
    }
    Z[(size_t)row * CH + c] = m;
}

// ---------- fused bnrelu + masked segment max (1024 ch) ----------
__global__ __launch_bounds__(256)
void segmax_bnrelu_kernel(const float* __restrict__ H, const float* __restrict__ scale,
                          const float* __restrict__ shift, const int* __restrict__ mask,
                          unsigned* __restrict__ pooled)
{
    const int b = blockIdx.x, nc = blockIdx.y, cg = blockIdx.z;
    const int c = (cg << 8) + threadIdx.x;
    const float sc = scale[c], sh = shift[c];
    float m = 0.f;
    const int n0 = nc << 8;
    for (int n = n0; n < n0 + 256; ++n) {
        if (mask[b * NPTS + n] == 1) {
            const float v = H[((size_t)b * NPTS + n) * 1024 + c];
            m = fmaxf(m, fmaxf(0.f, fmaf(v, sc, sh)));
        }
    }
    atomicMax(&pooled[(b << 10) + c], __float_as_uint(m));
}

// ---------- head: 8-row GEMM + BN(over 8) + ReLU, fused ----------
template<int KDIM>
__global__ __launch_bounds__(256)
void mlp8_kernel(const float* __restrict__ In, const float* __restrict__ W,
                 const float* __restrict__ bias, const float* __restrict__ g,
                 const float* __restrict__ be, float* __restrict__ Out)
{
    __shared__ float Ins[8 * KDIM];
    __shared__ float Ys[8][64];
    const int tid = threadIdx.x;
    for (int e = tid; e < 8 * KDIM; e += 256) Ins[e] = In[e];
    __syncthreads();
    const int cl = tid & 63;
    const int col = (blockIdx.x << 6) + cl;
    const int r0 = tid >> 6;
    float a0 = 0.f, a1 = 0.f;
    for (int k = 0; k < KDIM; ++k) {
        const float w = W[(size_t)k * 512 + col];
        a0 = fmaf(Ins[r0 * KDIM + k], w, a0);
        a1 = fmaf(Ins[(r0 + 4) * KDIM + k], w, a1);
    }
    const float bi = bias[col];
    Ys[r0][cl] = a0 + bi;
    Ys[r0 + 4][cl] = a1 + bi;
    __syncthreads();
    if (tid < 64) {
        float s = 0.f, ss = 0.f;
        #pragma unroll
        for (int r = 0; r < 8; ++r) { const float v = Ys[r][tid]; s += v; ss = fmaf(v, v, ss); }
        const float mean = s * 0.125f;
        const float var = fmaxf(ss * 0.125f - mean * mean, 0.f);
        const float sc = g[col] * rsqrtf(var + 1e-5f);
        const float sh = be[col] - mean * sc;
        #pragma unroll
        for (int r = 0; r < 8; ++r)
            Out[r * 512 + col] = fmaxf(0.f, fmaf(Ys[r][tid], sc, sh));
    }
}

// ---------- launcher ----------
extern "C" void kernel_launch(void* const* d_in, const int* in_sizes, int n_in,
                              void* d_out, int out_size, void* d_ws, size_t ws_size,
                              hipStream_t stream)
{
    const float* x    = (const float*)d_in[0];
    const int*   mask = (const int*)d_in[1];
    const float* w_m1a = (const float*)d_in[2];
    const float* b_m1a = (const float*)d_in[3];
    const float* g_m1a = (const float*)d_in[4];
    const float* be_m1a = (const float*)d_in[5];
    const float* w_m1b = (const float*)d_in[6];
    const float* b_m1b = (const float*)d_in[7];
    const float* g_m1b = (const float*)d_in[8];
    const float* be_m1b = (const float*)d_in[9];
    const float* w_m1c = (const float*)d_in[10];
    const float* b_m1c = (const float*)d_in[11];
    const float* g_m1c = (const float*)d_in[12];
    const float* be_m1c = (const float*)d_in[13];
    const float* w_gl1 = (const float*)d_in[14];
    const float* b_gl1 = (const float*)d_in[15];
    const float* g_gl1 = (const float*)d_in[16];
    const float* be_gl1 = (const float*)d_in[17];
    const float* w_gl2 = (const float*)d_in[18];
    const float* b_gl2 = (const float*)d_in[19];
    const float* g_gl2 = (const float*)d_in[20];
    const float* be_gl2 = (const float*)d_in[21];
    const float* w_m2a = (const float*)d_in[22];
    const float* b_m2a = (const float*)d_in[23];
    const float* g_m2a = (const float*)d_in[24];
    const float* be_m2a = (const float*)d_in[25];
    const float* w_m2b = (const float*)d_in[26];
    const float* b_m2b = (const float*)d_in[27];
    const float* g_m2b = (const float*)d_in[28];
    const float* be_m2b = (const float*)d_in[29];

    float* ws = (float*)d_ws;
    int*   idx  = (int*)ws;                 // 262144 ints (1 MB)
    float* h0   = ws + 262144;              // 16384*12
    float* bufA = h0 + 196608;              // 16384*64
    float* bufB = bufA + 1048576;           // 16384*64
    float* bufC = bufB + 1048576;           // 16384*128
    float* bufD = bufC + 2097152;           // 16384*128
    float* bufE = bufD + 2097152;           // 16384*1024
    float* pooled = bufE + 16777216;        // 8*1024
    float* y1     = pooled + 8192;          // 8*512
    float* psum   = y1 + 4096;              // 32*1024
    float* psumsq = psum + 32768;           // 32*1024
    float* scale  = psumsq + 32768;         // 1024
    float* shift  = scale + 1024;           // 1024

    hipMemsetAsync(pooled, 0, 8 * 1024 * sizeof(float), stream);

    knn_cov_kernel<<<4096, 256, 0, stream>>>(x, mask, idx, h0);

    // m1a: 12 -> 64  (raw output in bufA; bn folded into m1b's X load)
    gemm_bias_kernel<false><<<dim3(256, 1), 256, 0, stream>>>(h0, w_m1a, b_m1a, nullptr, nullptr, bufA, 12, 64);
    stats_partial_kernel<<<dim3(1, 32), 256, 0, stream>>>(bufA, psum, psumsq, 64);
    stats_final_kernel<<<1, 256, 0, stream>>>(psum, psumsq, g_m1a, be_m1a, scale, shift, 64);

    // m1b: 64 -> 64 (applies bn_m1a to X on load)
    gemm_bias_kernel<true><<<dim3(256, 1), 256, 0, stream>>>(bufA, w_m1b, b_m1b, scale, shift, bufB, 64, 64);
    stats_partial_kernel<<<dim3(1, 32), 256, 0, stream>>>(bufB, psum, psumsq, 64);
    stats_final_kernel<<<1, 256, 0, stream>>>(psum, psumsq, g_m1b, be_m1b, scale, shift, 64);

    // m1c: 64 -> 64 (applies bn_m1b to X on load)
    gemm_bias_kernel<true><<<dim3(256, 1), 256, 0, stream>>>(bufB, w_m1c, b_m1c, scale, shift, bufA, 64, 64);
    stats_partial_kernel<<<dim3(1, 32), 256, 0, stream>>>(bufA, psum, psumsq, 64);
    stats_final_kernel<<<1, 256, 0, stream>>>(psum, psumsq, g_m1c, be_m1c, scale, shift, 64);

    // gather-max (64 ch), applies bn_m1c to gathered elements
    gathermax_bn_kernel<64><<<4096, 256, 0, stream>>>(bufA, idx, scale, shift, bufB);

    // gl1: 64 -> 128 (X already bn'd)
    gemm_bias_kernel<false><<<dim3(256, 2), 256, 0, stream>>>(bufB, w_gl1, b_gl1, nullptr, nullptr, bufC, 64, 128);
    stats_partial_kernel<<<dim3(2, 32), 256, 0, stream>>>(bufC, psum, psumsq, 128);
    stats_final_kernel<<<1, 256, 0, stream>>>(psum, psumsq, g_gl1, be_gl1, scale, shift, 128);

    // gather-max (128 ch), applies bn_gl1
    gathermax_bn_kernel<128><<<8192, 256, 0, stream>>>(bufC, idx, scale, shift, bufD);

    // gl2: 128 -> 1024
    gemm_bias_kernel<false><<<dim3(256, 16), 256, 0, stream>>>(bufD, w_gl2, b_gl2, nullptr, nullptr, bufE, 128, 1024);
    stats_partial_kernel<<<dim3(16, 32), 256, 0, stream>>>(bufE, psum, psumsq, 1024);
    stats_final_kernel<<<4, 256, 0, stream>>>(psum, psumsq, g_gl2, be_gl2, scale, shift, 1024);

    // fused bnrelu + masked segment-max pool
    segmax_bnrelu_kernel<<<dim3(8, 8, 4), 256, 0, stream>>>(bufE, scale, shift, mask, (unsigned*)pooled);

    // head
    mlp8_kernel<1024><<<8, 256, 0, stream>>>(pooled, w_m2a, b_m2a, g_m2a, be_m2a, y1);
    mlp8_kernel<512><<<8, 256, 0, stream>>>(y1, w_m2b, b_m2b, g_m2b, be_m2b, (float*)d_out);
}

// Round 5
// 458.267 us; speedup vs baseline: 2.1378x; 1.2867x over previous
//
#include <hip/hip_runtime.h>
#include <hip/hip_bf16.h>
#include <stdint.h>
#include <math.h>

#define NPTS 2048
#define BSZ 8
#define KNN 16
#define MROWS (BSZ * NPTS)   // 16384

typedef __attribute__((ext_vector_type(8))) short bf16x8;
typedef __attribute__((ext_vector_type(4))) float f32x4;

__device__ __forceinline__ unsigned short f2bf(float f) {
    __hip_bfloat16 h = __float2bfloat16(f);
    return *(unsigned short*)&h;
}
__device__ __forceinline__ float bf2f(unsigned short u) {
    return __uint_as_float(((unsigned)u) << 16);
}

// ---------- helpers ----------
__device__ __forceinline__ unsigned sortable32(float f) {
    unsigned u = __float_as_uint(f);
    return u ^ ((unsigned)((int)u >> 31) | 0x80000000u);
}

__device__ __forceinline__ void cas_asc(unsigned long long &a, unsigned long long &b) {
    unsigned long long lo = a < b ? a : b;
    unsigned long long hi = a < b ? b : a;
    a = lo; b = hi;
}

// ---------- KNN + covariance (R2-proven: u64 insertion top-16, no spill) ----------
__global__ __launch_bounds__(256)
void knn_cov_kernel(const float* __restrict__ x, const int* __restrict__ mask,
                    int* __restrict__ idx_out, float* __restrict__ h0)
{
    __shared__ float4 cand[NPTS];
    const int tid  = threadIdx.x;
    const int wave = tid >> 6;
    const int lane = tid & 63;
    const int b = blockIdx.x >> 9;
    const int q = ((blockIdx.x & 511) << 2) + wave;
    const float* xb = x + (size_t)b * 3 * NPTS;
    const int*   mb = mask + b * NPTS;

    for (int m = tid; m < NPTS; m += 256) {
        float px = xb[m], py = xb[NPTS + m], pz = xb[2 * NPTS + m];
        float sq = px * px + py * py + pz * pz;
        if (mb[m] != 1) sq = INFINITY;
        cand[m] = make_float4(px, py, pz, sq);
    }
    __syncthreads();

    const float4 qc = cand[q];
    const float qx = qc.x, qy = qc.y, qz = qc.z;
    const float sqn = qx * qx + qy * qy + qz * qz;

    // per-lane top-16 via branchless bubble insertion (ascending)
    unsigned long long list[16];
    #pragma unroll
    for (int i = 0; i < 16; ++i) list[i] = ~0ull;
    #pragma unroll
    for (int t = 0; t < 32; ++t) {
        const int m = t * 64 + lane;
        const float4 c = cand[m];
        const float dot = qx * c.x + qy * c.y + qz * c.z;
        const float d = fmaf(-2.f, dot, sqn + c.w);
        unsigned long long cur = ((unsigned long long)sortable32(d) << 32) | (unsigned)m;
        #pragma unroll
        for (int i = 0; i < 16; ++i) {
            const bool lt = cur < list[i];
            const unsigned long long lo = lt ? cur : list[i];
            const unsigned long long hi = lt ? list[i] : cur;
            list[i] = lo; cur = hi;
        }
    }

    // 6 cross-lane bitonic merge rounds: keep lowest 16 of (mine, partner)
    #pragma unroll
    for (int p = 1; p <= 32; p <<= 1) {
        unsigned long long c2[16];
        #pragma unroll
        for (int i = 0; i < 16; ++i) {
            const unsigned long long pr = __shfl_xor(list[15 - i], p, 64);
            c2[i] = list[i] < pr ? list[i] : pr;
        }
        #pragma unroll
        for (int j = 8; j > 0; j >>= 1) {
            #pragma unroll
            for (int i = 0; i < 16; ++i) {
                const int l = i ^ j;
                if (l > i) cas_asc(c2[i], c2[l]);
            }
        }
        #pragma unroll
        for (int i = 0; i < 16; ++i) list[i] = c2[i];
    }

    const int gq = b * NPTS + q;
    if (lane < KNN)
        idx_out[gq * KNN + lane] = b * NPTS + (int)(unsigned)list[lane];

    const int ml = (int)(unsigned)list[lane & 15];
    const float4 nb = cand[ml];
    float sx = nb.x, sy = nb.y, sz = nb.z;
    #pragma unroll
    for (int m = 1; m < 16; m <<= 1) {
        sx += __shfl_xor(sx, m, 64); sy += __shfl_xor(sy, m, 64); sz += __shfl_xor(sz, m, 64);
    }
    const float mx = sx * 0.0625f, my = sy * 0.0625f, mz = sz * 0.0625f;
    const float cx = nb.x - mx, cy = nb.y - my, cz = nb.z - mz;
    float xx = cx * cx, xy = cx * cy, xz = cx * cz;
    float yy = cy * cy, yz = cy * cz, zz = cz * cz;
    #pragma unroll
    for (int m = 1; m < 16; m <<= 1) {
        xx += __shfl_xor(xx, m, 64); xy += __shfl_xor(xy, m, 64); xz += __shfl_xor(xz, m, 64);
        yy += __shfl_xor(yy, m, 64); yz += __shfl_xor(yz, m, 64); zz += __shfl_xor(zz, m, 64);
    }
    if (lane == 0) {
        float* o = h0 + (size_t)gq * 12;
        o[0] = qx; o[1] = qy; o[2] = qz;
        o[3] = xx; o[4] = xy; o[5] = xz;
        o[6] = xy; o[7] = yy; o[8] = yz;
        o[9] = xz; o[10] = yz; o[11] = zz;
    }
}

// ---------- fp32 GEMM (small layers): Y = bnx(X) @ W + bias ----------
template<bool BNX>
__global__ __launch_bounds__(256)
void gemm_bias_kernel(const float* __restrict__ X, const float* __restrict__ W,
                      const float* __restrict__ bias,
                      const float* __restrict__ xscale, const float* __restrict__ xshift,
                      float* __restrict__ Y, int K, int C)
{
    __shared__ float Xs[16][65];
    __shared__ float Ws[16][65];
    const int tid = threadIdx.x;
    const int bm = blockIdx.x << 6;
    const int bn = blockIdx.y << 6;
    const int ty = tid >> 4, tx = tid & 15;
    float acc[4][4] = {};
    for (int k0 = 0; k0 < K; k0 += 16) {
        #pragma unroll
        for (int e = tid; e < 1024; e += 256) {
            const int m = e >> 4, k = e & 15;
            float v = 0.f;
            if (k0 + k < K) {
                v = X[(size_t)(bm + m) * K + k0 + k];
                if (BNX) v = fmaxf(0.f, fmaf(v, xscale[k0 + k], xshift[k0 + k]));
            }
            Xs[k][m] = v;
        }
        #pragma unroll
        for (int e = tid; e < 1024; e += 256) {
            const int k = e >> 6, n = e & 63;
            Ws[k][n] = (k0 + k < K) ? W[(size_t)(k0 + k) * C + bn + n] : 0.f;
        }
        __syncthreads();
        #pragma unroll
        for (int k = 0; k < 16; ++k) {
            float a[4], bb[4];
            #pragma unroll
            for (int i = 0; i < 4; ++i) a[i] = Xs[k][ty * 4 + i];
            #pragma unroll
            for (int j = 0; j < 4; ++j) bb[j] = Ws[k][tx * 4 + j];
            #pragma unroll
            for (int i = 0; i < 4; ++i)
                #pragma unroll
                for (int j = 0; j < 4; ++j)
                    acc[i][j] = fmaf(a[i], bb[j], acc[i][j]);
        }
        __syncthreads();
    }
    #pragma unroll
    for (int i = 0; i < 4; ++i) {
        const int r = bm + ty * 4 + i;
        #pragma unroll
        for (int j = 0; j < 4; ++j) {
            const int cc = bn + tx * 4 + j;
            Y[(size_t)r * C + cc] = acc[i][j] + bias[cc];
        }
    }
}

// ---------- w_gl2 -> split bf16 transposed [n][k]: hi + lo(residual) ----------
__global__ void cvt_wgl2_kernel(const float* __restrict__ w,
                                unsigned short* __restrict__ wT_hi,
                                unsigned short* __restrict__ wT_lo)
{
    const int t = blockIdx.x * 256 + threadIdx.x;   // t = n*128 + k
    const int n = t >> 7, k = t & 127;
    const float v = w[(size_t)k * 1024 + n];
    const unsigned short hi = f2bf(v);
    wT_hi[t] = hi;
    wT_lo[t] = f2bf(v - bf2f(hi));
}

// ---------- gl2 MFMA GEMM (split-bf16, 3 passes): Y fp32 = A @ W + bias ----------
// grid (M/128, 1024/128), 256 threads = 4 waves (2x2), 64x64 per wave.
__global__ __launch_bounds__(256)
void gemm_gl2_mfma(const unsigned short* __restrict__ Ahi,  // [M][128]
                   const unsigned short* __restrict__ Alo,
                   const unsigned short* __restrict__ Whi,  // [1024][128]
                   const unsigned short* __restrict__ Wlo,
                   const float* __restrict__ bias,
                   float* __restrict__ Y)                   // [M][1024] fp32
{
    const int wave = threadIdx.x >> 6, lane = threadIdx.x & 63;
    const int wm = wave >> 1, wn = wave & 1;
    const int bm = blockIdx.x * 128 + wm * 64;
    const int bn = blockIdx.y * 128 + wn * 64;
    const int lrow = lane & 15;
    const int lk = (lane >> 4) * 8;
    f32x4 acc[4][4] = {};
    #pragma unroll
    for (int ks = 0; ks < 4; ++ks) {
        const int k0 = ks * 32 + lk;
        bf16x8 ah[4], al[4], bh[4], bl[4];
        #pragma unroll
        for (int mf = 0; mf < 4; ++mf) {
            const size_t off = (size_t)(bm + mf * 16 + lrow) * 128 + k0;
            ah[mf] = *(const bf16x8*)(Ahi + off);
            al[mf] = *(const bf16x8*)(Alo + off);
        }
        #pragma unroll
        for (int nf = 0; nf < 4; ++nf) {
            const size_t off = (size_t)(bn + nf * 16 + lrow) * 128 + k0;
            bh[nf] = *(const bf16x8*)(Whi + off);
            bl[nf] = *(const bf16x8*)(Wlo + off);
        }
        #pragma unroll
        for (int mf = 0; mf < 4; ++mf)
            #pragma unroll
            for (int nf = 0; nf < 4; ++nf) {
                acc[mf][nf] = __builtin_amdgcn_mfma_f32_16x16x32_bf16(ah[mf], bh[nf], acc[mf][nf], 0, 0, 0);
                acc[mf][nf] = __builtin_amdgcn_mfma_f32_16x16x32_bf16(ah[mf], bl[nf], acc[mf][nf], 0, 0, 0);
                acc[mf][nf] = __builtin_amdgcn_mfma_f32_16x16x32_bf16(al[mf], bh[nf], acc[mf][nf], 0, 0, 0);
            }
    }
    const int r0 = (lane >> 4) * 4, cc = lane & 15;
    #pragma unroll
    for (int mf = 0; mf < 4; ++mf) {
        const int row = bm + mf * 16 + r0;
        #pragma unroll
        for (int nf = 0; nf < 4; ++nf) {
            const int col = bn + nf * 16 + cc;
            const float bv = bias[col];
            #pragma unroll
            for (int r = 0; r < 4; ++r)
                Y[(size_t)(row + r) * 1024 + col] = acc[mf][nf][r] + bv;
        }
    }
}

// ---------- BN stats: fp32 (chunked partials) ----------
__global__ __launch_bounds__(256)
void stats_partial_kernel(const float* __restrict__ Y, float* __restrict__ psum,
                          float* __restrict__ psumsq, int C, int rows)
{
    const int c = (blockIdx.x << 6) + (threadIdx.x & 63);
    const int rg = threadIdx.x >> 6;
    const int r0 = blockIdx.y * rows;
    float s = 0.f, ss = 0.f;
    for (int r = r0 + rg; r < r0 + rows; r += 4) {
        const float v = Y[(size_t)r * C + c];
        s += v; ss = fmaf(v, v, ss);
    }
    __shared__ float ls[256], lss[256];
    ls[threadIdx.x] = s; lss[threadIdx.x] = ss;
    __syncthreads();
    if (threadIdx.x < 64) {
        s  = ls[threadIdx.x]  + ls[threadIdx.x + 64]  + ls[threadIdx.x + 128]  + ls[threadIdx.x + 192];
        ss = lss[threadIdx.x] + lss[threadIdx.x + 64] + lss[threadIdx.x + 128] + lss[threadIdx.x + 192];
        psum[blockIdx.y * C + c] = s;
        psumsq[blockIdx.y * C + c] = ss;
    }
}

__global__ void stats_final_kernel(const float* __restrict__ psum, const float* __restrict__ psumsq,
                                   const float* __restrict__ g, const float* __restrict__ be,
                                   float* __restrict__ scale, float* __restrict__ shift,
                                   int C, int nchunks)
{
    const int c = blockIdx.x * 256 + threadIdx.x;
    if (c >= C) return;
    float s = 0.f, ss = 0.f;
    for (int i = 0; i < nchunks; ++i) { s += psum[i * C + c]; ss += psumsq[i * C + c]; }
    const float invM = 1.f / (float)MROWS;
    const float mean = s * invM;
    const float var = fmaxf(ss * invM - mean * mean, 0.f);
    const float sc = g[c] * rsqrtf(var + 1e-5f);
    scale[c] = sc;
    shift[c] = be[c] - mean * sc;
}

// ---------- gather-max + BN, 64 ch, float4 ----------
__global__ __launch_bounds__(256)
void gathermax_bn64(const float* __restrict__ Hin, const int* __restrict__ idx,
                    const float* __restrict__ scale, const float* __restrict__ shift,
                    float* __restrict__ Z)
{
    const int c4 = threadIdx.x & 15;
    const int rr = threadIdx.x >> 4;
    const int row = blockIdx.x * 16 + rr;
    const int* ip = idx + (size_t)row * KNN;
    const float4 sc = ((const float4*)scale)[c4], sh = ((const float4*)shift)[c4];
    float4 m = {0,0,0,0};
    #pragma unroll
    for (int k = 0; k < KNN; ++k) {
        const int j = ip[k];
        const float4 v = *(const float4*)(Hin + (size_t)j * 64 + c4 * 4);
        m.x = fmaxf(m.x, fmaf(v.x, sc.x, sh.x));
        m.y = fmaxf(m.y, fmaf(v.y, sc.y, sh.y));
        m.z = fmaxf(m.z, fmaf(v.z, sc.z, sh.z));
        m.w = fmaxf(m.w, fmaf(v.w, sc.w, sh.w));
    }
    ((float4*)(Z + (size_t)row * 64))[c4] = m;
}

// ---------- gather-max + BN, 128 ch, split-bf16 out (hi + residual lo) ----------
__global__ __launch_bounds__(256)
void gathermax_bn128_split(const float* __restrict__ Hin, const int* __restrict__ idx,
                           const float* __restrict__ scale, const float* __restrict__ shift,
                           unsigned short* __restrict__ Zhi, unsigned short* __restrict__ Zlo)
{
    const int c4 = threadIdx.x & 31;
    const int rr = threadIdx.x >> 5;
    const int row = blockIdx.x * 8 + rr;
    const int* ip = idx + (size_t)row * KNN;
    const float4 sc = ((const float4*)scale)[c4], sh = ((const float4*)shift)[c4];
    float4 m = {0,0,0,0};
    #pragma unroll
    for (int k = 0; k < KNN; ++k) {
        const int j = ip[k];
        const float4 v = *(const float4*)(Hin + (size_t)j * 128 + c4 * 4);
        m.x = fmaxf(m.x, fmaf(v.x, sc.x, sh.x));
        m.y = fmaxf(m.y, fmaf(v.y, sc.y, sh.y));
        m.z = fmaxf(m.z, fmaf(v.z, sc.z, sh.z));
        m.w = fmaxf(m.w, fmaf(v.w, sc.w, sh.w));
    }
    ushort4 hi, lo;
    hi.x = f2bf(m.x); lo.x = f2bf(m.x - bf2f(hi.x));
    hi.y = f2bf(m.y); lo.y = f2bf(m.y - bf2f(hi.y));
    hi.z = f2bf(m.z); lo.z = f2bf(m.z - bf2f(hi.z));
    hi.w = f2bf(m.w); lo.w = f2bf(m.w - bf2f(hi.w));
    *(ushort4*)(Zhi + (size_t)row * 128 + c4 * 4) = hi;
    *(ushort4*)(Zlo + (size_t)row * 128 + c4 * 4) = lo;
}

// ---------- fused bnrelu + masked segment max, fp32, float4 ----------
// grid (8, 32): 64 points per chunk, 256 threads x 4 ch = 1024 ch
__global__ __launch_bounds__(256)
void segmax_bnrelu_f32(const float* __restrict__ Y, const float* __restrict__ scale,
                       const float* __restrict__ shift, const int* __restrict__ mask,
                       unsigned* __restrict__ pooled)
{
    __shared__ int mk[64];
    const int b = blockIdx.x, nc = blockIdx.y;
    const int n0 = nc * 64;
    if (threadIdx.x < 64) mk[threadIdx.x] = mask[b * NPTS + n0 + threadIdx.x];
    __syncthreads();
    const int c4 = threadIdx.x;
    const float4 sc = ((const float4*)scale)[c4], sh = ((const float4*)shift)[c4];
    float4 m = {0,0,0,0};
    for (int n = 0; n < 64; ++n) {
        if (mk[n]) {
            const float4 v = ((const float4*)(Y + ((size_t)b * NPTS + n0 + n) * 1024))[c4];
            m.x = fmaxf(m.x, fmaf(v.x, sc.x, sh.x));
            m.y = fmaxf(m.y, fmaf(v.y, sc.y, sh.y));
            m.z = fmaxf(m.z, fmaf(v.z, sc.z, sh.z));
            m.w = fmaxf(m.w, fmaf(v.w, sc.w, sh.w));
        }
    }
    m.x = fmaxf(m.x, 0.f); m.y = fmaxf(m.y, 0.f); m.z = fmaxf(m.z, 0.f); m.w = fmaxf(m.w, 0.f);
    atomicMax(&pooled[b * 1024 + c4 * 4 + 0], __float_as_uint(m.x));
    atomicMax(&pooled[b * 1024 + c4 * 4 + 1], __float_as_uint(m.y));
    atomicMax(&pooled[b * 1024 + c4 * 4 + 2], __float_as_uint(m.z));
    atomicMax(&pooled[b * 1024 + c4 * 4 + 3], __float_as_uint(m.w));
}

// ---------- head: 8-row GEMM + BN(8) + ReLU, 4-way K split ----------
template<int KDIM>
__global__ __launch_bounds__(256)
void mlp8_kernel(const float* __restrict__ In, const float* __restrict__ W,
                 const float* __restrict__ bias, const float* __restrict__ g,
                 const float* __restrict__ be, float* __restrict__ Out)
{
    __shared__ float Ins[8 * KDIM];
    __shared__ float part[4][8][64];
    const int tid = threadIdx.x;
    for (int e = tid; e < 8 * KDIM; e += 256) Ins[e] = In[e];
    __syncthreads();
    const int kg = tid >> 6, cl = tid & 63;
    const int col = (blockIdx.x << 6) + cl;
    float a[8] = {};
    const int k1 = (kg + 1) * (KDIM / 4);
    for (int k = kg * (KDIM / 4); k < k1; ++k) {
        const float w = W[(size_t)k * 512 + col];
        #pragma unroll
        for (int r = 0; r < 8; ++r) a[r] = fmaf(Ins[r * KDIM + k], w, a[r]);
    }
    #pragma unroll
    for (int r = 0; r < 8; ++r) part[kg][r][cl] = a[r];
    __syncthreads();
    if (tid < 64) {
        const int c2 = (blockIdx.x << 6) + tid;
        const float bv = bias[c2];
        float y[8], s = 0.f, ss = 0.f;
        #pragma unroll
        for (int r = 0; r < 8; ++r) {
            y[r] = part[0][r][tid] + part[1][r][tid] + part[2][r][tid] + part[3][r][tid] + bv;
            s += y[r]; ss = fmaf(y[r], y[r], ss);
        }
        const float mean = s * 0.125f;
        const float var = fmaxf(ss * 0.125f - mean * mean, 0.f);
        const float sc = g[c2] * rsqrtf(var + 1e-5f);
        const float sh = be[c2] - mean * sc;
        #pragma unroll
        for (int r = 0; r < 8; ++r)
            Out[r * 512 + c2] = fmaxf(0.f, fmaf(y[r], sc, sh));
    }
}

// ---------- launcher ----------
extern "C" void kernel_launch(void* const* d_in, const int* in_sizes, int n_in,
                              void* d_out, int out_size, void* d_ws, size_t ws_size,
                              hipStream_t stream)
{
    const float* x    = (const float*)d_in[0];
    const int*   mask = (const int*)d_in[1];
    const float* w_m1a = (const float*)d_in[2];
    const float* b_m1a = (const float*)d_in[3];
    const float* g_m1a = (const float*)d_in[4];
    const float* be_m1a = (const float*)d_in[5];
    const float* w_m1b = (const float*)d_in[6];
    const float* b_m1b = (const float*)d_in[7];
    const float* g_m1b = (const float*)d_in[8];
    const float* be_m1b = (const float*)d_in[9];
    const float* w_m1c = (const float*)d_in[10];
    const float* b_m1c = (const float*)d_in[11];
    const float* g_m1c = (const float*)d_in[12];
    const float* be_m1c = (const float*)d_in[13];
    const float* w_gl1 = (const float*)d_in[14];
    const float* b_gl1 = (const float*)d_in[15];
    const float* g_gl1 = (const float*)d_in[16];
    const float* be_gl1 = (const float*)d_in[17];
    const float* w_gl2 = (const float*)d_in[18];
    const float* b_gl2 = (const float*)d_in[19];
    const float* g_gl2 = (const float*)d_in[20];
    const float* be_gl2 = (const float*)d_in[21];
    const float* w_m2a = (const float*)d_in[22];
    const float* b_m2a = (const float*)d_in[23];
    const float* g_m2a = (const float*)d_in[24];
    const float* be_m2a = (const float*)d_in[25];
    const float* w_m2b = (const float*)d_in[26];
    const float* b_m2b = (const float*)d_in[27];
    const float* g_m2b = (const float*)d_in[28];
    const float* be_m2b = (const float*)d_in[29];

    float* ws = (float*)d_ws;
    int*   idx  = (int*)ws;                              // 262144 slots
    float* h0   = ws + 262144;                           // +196608
    float* bufA = ws + 458752;                           // +1048576
    float* bufB = ws + 1507328;                          // +1048576
    float* bufC = ws + 2555904;                          // +2097152 (16384x128 f32)
    unsigned short* Ahi = (unsigned short*)(ws + 4653056);   // 16384x128 bf16 (+1048576 slots)
    unsigned short* Alo = (unsigned short*)(ws + 5701632);   // +1048576
    unsigned short* wTh = (unsigned short*)(ws + 6750208);   // 1024x128 bf16 (+65536)
    unsigned short* wTl = (unsigned short*)(ws + 6815744);   // +65536
    float* bufE  = ws + 6881280;                         // 16384x1024 f32 (+16777216)
    float* pooled = ws + 23658496;                       // +8192
    float* y1     = ws + 23666688;                       // +4096
    float* psum   = ws + 23670784;                       // +65536
    float* psumsq = ws + 23736320;                       // +65536
    float* scale  = ws + 23801856;                       // +1024
    float* shift  = ws + 23802880;                       // +1024  (end 23803904 ~ 95.2 MB)

    hipMemsetAsync(pooled, 0, 8 * 1024 * sizeof(float), stream);
    cvt_wgl2_kernel<<<512, 256, 0, stream>>>(w_gl2, wTh, wTl);

    knn_cov_kernel<<<4096, 256, 0, stream>>>(x, mask, idx, h0);

    // m1a: 12 -> 64
    gemm_bias_kernel<false><<<dim3(256, 1), 256, 0, stream>>>(h0, w_m1a, b_m1a, nullptr, nullptr, bufA, 12, 64);
    stats_partial_kernel<<<dim3(1, 64), 256, 0, stream>>>(bufA, psum, psumsq, 64, 256);
    stats_final_kernel<<<1, 256, 0, stream>>>(psum, psumsq, g_m1a, be_m1a, scale, shift, 64, 64);

    // m1b: 64 -> 64 (bn_m1a folded into X load)
    gemm_bias_kernel<true><<<dim3(256, 1), 256, 0, stream>>>(bufA, w_m1b, b_m1b, scale, shift, bufB, 64, 64);
    stats_partial_kernel<<<dim3(1, 64), 256, 0, stream>>>(bufB, psum, psumsq, 64, 256);
    stats_final_kernel<<<1, 256, 0, stream>>>(psum, psumsq, g_m1b, be_m1b, scale, shift, 64, 64);

    // m1c: 64 -> 64 (bn_m1b folded)
    gemm_bias_kernel<true><<<dim3(256, 1), 256, 0, stream>>>(bufB, w_m1c, b_m1c, scale, shift, bufA, 64, 64);
    stats_partial_kernel<<<dim3(1, 64), 256, 0, stream>>>(bufA, psum, psumsq, 64, 256);
    stats_final_kernel<<<1, 256, 0, stream>>>(psum, psumsq, g_m1c, be_m1c, scale, shift, 64, 64);

    // gather-max 64 (bn_m1c folded)
    gathermax_bn64<<<1024, 256, 0, stream>>>(bufA, idx, scale, shift, bufB);

    // gl1: 64 -> 128
    gemm_bias_kernel<false><<<dim3(256, 2), 256, 0, stream>>>(bufB, w_gl1, b_gl1, nullptr, nullptr, bufC, 64, 128);
    stats_partial_kernel<<<dim3(2, 64), 256, 0, stream>>>(bufC, psum, psumsq, 128, 256);
    stats_final_kernel<<<1, 256, 0, stream>>>(psum, psumsq, g_gl1, be_gl1, scale, shift, 128, 64);

    // gather-max 128 (bn_gl1 folded) -> split-bf16 A for gl2
    gathermax_bn128_split<<<2048, 256, 0, stream>>>(bufC, idx, scale, shift, Ahi, Alo);

    // gl2: 128 -> 1024, split-bf16 MFMA (3 passes), fp32 out
    gemm_gl2_mfma<<<dim3(128, 8), 256, 0, stream>>>(Ahi, Alo, wTh, wTl, b_gl2, bufE);
    stats_partial_kernel<<<dim3(16, 64), 256, 0, stream>>>(bufE, psum, psumsq, 1024, 256);
    stats_final_kernel<<<4, 256, 0, stream>>>(psum, psumsq, g_gl2, be_gl2, scale, shift, 1024, 64);

    // fused bnrelu + masked segment-max
    segmax_bnrelu_f32<<<dim3(8, 32), 256, 0, stream>>>(bufE, scale, shift, mask, (unsigned*)pooled);

    // head
    mlp8_kernel<1024><<<8, 256, 0, stream>>>(pooled, w_m2a, b_m2a, g_m2a, be_m2a, y1);
    mlp8_kernel<512><<<8, 256, 0, stream>>>(y1, w_m2b, b_m2b, g_m2b, be_m2b, (float*)d_out);
}